// Round 1
// baseline (394.248 us; speedup 1.0000x reference)
//
#include <hip/hip_runtime.h>
#include <math.h>

#define C_FINE   100
#define C_MID    20
#define C_COARSE 5
#define D        128
#define NROWS    262144
#define NPAIRS   4950   // 100*99/2

// ws layout in floats
#define FP_OFF      0        // fine protos [100][128]
#define DM_OFF      12800    // mid dist table [20][20]
#define DC_OFF      13200    // coarse dist table [5][5]
#define ACC_OFF     13232    // 6 doubles (byte 52928, 8-aligned)
#define PART_OFF    13312    // partials: P x PART_STRIDE
#define PART_STRIDE 12928    // 100*128 sums + 100 counts + pad

// ---------------- K1: per-block partial segment sums ----------------
__global__ __launch_bounds__(1024) void k1_partial(const float* __restrict__ rep,
                                                   const int* __restrict__ tgt,
                                                   float* __restrict__ ws, int P) {
    __shared__ float sm[PART_STRIDE];
    const int t = threadIdx.x;
    for (int e = t; e < PART_STRIDE; e += 1024) sm[e] = 0.f;
    __syncthreads();

    const int d = t & 127;          // dim
    const int r = t >> 7;           // row-in-group 0..7
    const int NG = NROWS / 8;       // 32768 row-groups

    int g = blockIdx.x;
    if (g < NG) {
        int row = g * 8 + r;
        float v = rep[row * D + d];
        int   c = tgt[row];
        for (;;) {
            int gn = g + P;
            if (gn < NG) {
                int rown = gn * 8 + r;
                float vn = rep[rown * D + d];   // prefetch next
                int   cn = tgt[rown];
                atomicAdd(&sm[c * D + d], v);
                if (d == 0) atomicAdd(&sm[12800 + c], 1.0f);
                v = vn; c = cn; g = gn;
            } else {
                atomicAdd(&sm[c * D + d], v);
                if (d == 0) atomicAdd(&sm[12800 + c], 1.0f);
                break;
            }
        }
    }
    __syncthreads();
    float* out = ws + PART_OFF + (size_t)blockIdx.x * PART_STRIDE;
    for (int e = t; e < PART_STRIDE; e += 1024) out[e] = sm[e];
}

// ---------------- K2: reduce partials -> fine prototypes ----------------
__global__ __launch_bounds__(256) void k2_reduce(const float* __restrict__ part,
                                                 float* __restrict__ fineP, int P) {
    const int t = threadIdx.x;
    const int c = blockIdx.x * 2 + (t >> 7);
    const int d = t & 127;
    float s = 0.f, cnt = 0.f;
    for (int b = 0; b < P; ++b) {
        s   += part[(size_t)b * PART_STRIDE + c * D + d];
        cnt += part[(size_t)b * PART_STRIDE + 12800 + c];
    }
    fineP[c * D + d] = s / fmaxf(cnt, 1.0f);
}

// ---------------- K3: hierarchy + distance tables ----------------
__global__ __launch_bounds__(256) void k3_hier(const float* __restrict__ fineP,
                                               const int* __restrict__ f2m,
                                               const int* __restrict__ f2c,
                                               float* __restrict__ ws) {
    __shared__ float midP[C_MID * 129];     // stride 129: (m+d)%32 banks
    __shared__ float coarP[C_COARSE * 129];
    __shared__ int   m2c[C_MID];
    const int t = threadIdx.x;

    for (int e = t; e < C_MID * D; e += 256) {
        int m = e >> 7, d = e & 127;
        float s = 0.f; int cnt = 0;
        for (int f = 0; f < C_FINE; ++f)
            if (f2m[f] == m) { s += fineP[f * D + d]; ++cnt; }
        midP[m * 129 + d] = s / (float)max(cnt, 1);
    }
    if (t < C_MID) {
        int mx = -2147483647;
        for (int f = 0; f < C_FINE; ++f)
            if (f2m[f] == t) mx = max(mx, f2c[f]);
        m2c[t] = mx;
    }
    __syncthreads();
    for (int e = t; e < C_COARSE * D; e += 256) {
        int cc = e >> 7, d = e & 127;
        float s = 0.f; int cnt = 0;
        for (int m = 0; m < C_MID; ++m)
            if (m2c[m] == cc) { s += midP[m * 129 + d]; ++cnt; }
        coarP[cc * 129 + d] = s / (float)max(cnt, 1);
    }
    __syncthreads();
    for (int e = t; e < C_MID * C_MID; e += 256) {
        int m1 = e / C_MID, m2 = e % C_MID;
        float ss = 0.f;
        for (int d = 0; d < D; ++d) {
            float df = midP[m1 * 129 + d] - midP[m2 * 129 + d];
            ss += df * df;
        }
        ws[DM_OFF + e] = sqrtf(ss + 1e-12f);
    }
    for (int e = t; e < C_COARSE * C_COARSE; e += 256) {
        int c1 = e / C_COARSE, c2 = e % C_COARSE;
        float ss = 0.f;
        for (int d = 0; d < D; ++d) {
            float df = coarP[c1 * 129 + d] - coarP[c2 * 129 + d];
            ss += df * df;
        }
        ws[DC_OFF + e] = sqrtf(ss + 1e-12f);
    }
    if (t < 6) ((double*)(ws + ACC_OFF))[t] = 0.0;   // zero accumulators
}

// ---------------- K4: all fine pairs -> 5 moments ----------------
__global__ __launch_bounds__(64) void k4_pairs(float* __restrict__ ws,
                                               const int* __restrict__ f2m,
                                               const int* __restrict__ f2c) {
    const int p = blockIdx.x * 64 + threadIdx.x;
    double st = 0, sp = 0, stp = 0, stt = 0, spp = 0;
    if (p < NPAIRS) {
        int i = 0, rem = p;
        while (rem >= C_FINE - 1 - i) { rem -= C_FINE - 1 - i; ++i; }
        int j = i + 1 + rem;

        const float4* Fi = (const float4*)(ws + FP_OFF + i * D);
        const float4* Fj = (const float4*)(ws + FP_OFF + j * D);
        float ss = 0.f;
        #pragma unroll
        for (int k = 0; k < D / 4; ++k) {
            float4 a = Fi[k], b = Fj[k];
            float dx = a.x - b.x, dy = a.y - b.y, dz = a.z - b.z, dw = a.w - b.w;
            ss += dx * dx + dy * dy + dz * dz + dw * dw;
        }
        float proto = sqrtf(ss + 1e-12f);
        float tree  = ws[DC_OFF + f2c[i] * C_COARSE + f2c[j]]
                    + ws[DM_OFF + f2m[i] * C_MID + f2m[j]];
        st = tree; sp = proto;
        stp = (double)tree * (double)proto;
        stt = (double)tree * (double)tree;
        spp = (double)proto * (double)proto;
    }
    for (int off = 32; off > 0; off >>= 1) {
        st  += __shfl_down(st, off);
        sp  += __shfl_down(sp, off);
        stp += __shfl_down(stp, off);
        stt += __shfl_down(stt, off);
        spp += __shfl_down(spp, off);
    }
    if (threadIdx.x == 0) {
        double* acc = (double*)(ws + ACC_OFF);
        atomicAdd(&acc[0], st);
        atomicAdd(&acc[1], sp);
        atomicAdd(&acc[2], stp);
        atomicAdd(&acc[3], stt);
        atomicAdd(&acc[4], spp);
    }
}

// ---------------- K5: finalize 1 - corr ----------------
__global__ void k5_final(const float* __restrict__ ws, float* __restrict__ out) {
    const double* acc = (const double*)(ws + ACC_OFF);
    double st = acc[0], sp = acc[1], stp = acc[2], stt = acc[3], spp = acc[4];
    const double n = (double)NPAIRS;
    double num = stp - st * sp / n;
    double dtt = stt - st * st / n;
    double dpp = spp - sp * sp / n;
    double corr = num / sqrt(dtt * dpp + 1e-12);
    out[0] = (float)(1.0 - corr);
}

extern "C" void kernel_launch(void* const* d_in, const int* in_sizes, int n_in,
                              void* d_out, int out_size, void* d_ws, size_t ws_size,
                              hipStream_t stream) {
    const float* rep = (const float*)d_in[0];
    const int*   tgt = (const int*)d_in[1];
    const int*   f2m = (const int*)d_in[2];
    const int*   f2c = (const int*)d_in[3];
    float* ws  = (float*)d_ws;
    float* out = (float*)d_out;

    long avail = (long)(ws_size / 4) - PART_OFF;
    int P = (int)(avail / PART_STRIDE);
    if (P > 512) P = 512;
    if (P < 1)   P = 1;

    hipLaunchKernelGGL(k1_partial, dim3(P), dim3(1024), 0, stream, rep, tgt, ws, P);
    hipLaunchKernelGGL(k2_reduce, dim3(C_FINE / 2), dim3(256), 0, stream,
                       ws + PART_OFF, ws + FP_OFF, P);
    hipLaunchKernelGGL(k3_hier, dim3(1), dim3(256), 0, stream,
                       ws + FP_OFF, f2m, f2c, ws);
    hipLaunchKernelGGL(k4_pairs, dim3((NPAIRS + 63) / 64), dim3(64), 0, stream,
                       ws, f2m, f2c);
    hipLaunchKernelGGL(k5_final, dim3(1), dim3(1), 0, stream, ws, out);
}

// Round 2
// 291.323 us; speedup vs baseline: 1.3533x; 1.3533x over previous
//
#include <hip/hip_runtime.h>
#include <math.h>

#define C_FINE   100
#define C_MID    20
#define C_COARSE 5
#define D        128
#define NROWS    262144
#define NPAIRS   4950   // 100*99/2

// ws layout in floats
#define FP_OFF      0        // fine protos [100][128]
#define DM_OFF      12800    // mid dist table [20][20]
#define DC_OFF      13200    // coarse dist table [5][5]
#define ACC_OFF     13232    // 6 doubles (byte 52928, 8-aligned)
#define PART_OFF    13312    // partials: P x PART_STRIDE
#define PART_STRIDE 12928    // 100*128 sums + 100 counts + pad
#define NBLK1       512

// ---------------- K1: per-block partial segment sums (8-deep MLP) ----------------
__global__ __launch_bounds__(512) void k1_partial(const float* __restrict__ rep,
                                                  const int* __restrict__ tgt,
                                                  float* __restrict__ ws) {
    __shared__ float sm[PART_STRIDE];
    const int t = threadIdx.x;
    for (int e = t; e < PART_STRIDE; e += 512) sm[e] = 0.f;
    __syncthreads();

    const int dl = t & 31;        // dim lane: owns dims dl, dl+32, dl+64, dl+96
    const int r  = t >> 5;        // row 0..15 within group
    const int NG = NROWS / 32;    // 8192 groups of 32 rows

    for (int g = blockIdx.x; g < NG; g += NBLK1) {
        const int row0 = g * 32 + r;
        const int row1 = row0 + 16;
        const int c0 = tgt[row0];
        const int c1 = tgt[row1];
        float v0[4], v1[4];
        #pragma unroll
        for (int k = 0; k < 4; ++k) v0[k] = rep[row0 * D + dl + 32 * k];
        #pragma unroll
        for (int k = 0; k < 4; ++k) v1[k] = rep[row1 * D + dl + 32 * k];
        #pragma unroll
        for (int k = 0; k < 4; ++k) atomicAdd(&sm[c0 * D + dl + 32 * k], v0[k]);
        #pragma unroll
        for (int k = 0; k < 4; ++k) atomicAdd(&sm[c1 * D + dl + 32 * k], v1[k]);
        if (dl == 0) {
            atomicAdd(&sm[12800 + c0], 1.0f);
            atomicAdd(&sm[12800 + c1], 1.0f);
        }
    }
    __syncthreads();
    float* out = ws + PART_OFF + (size_t)blockIdx.x * PART_STRIDE;
    for (int e = t; e < PART_STRIDE; e += 512) out[e] = sm[e];
}

// ---------------- K2: reduce partials -> fine prototypes (1 block per class) ----------------
__global__ __launch_bounds__(256) void k2_reduce(const float* __restrict__ part,
                                                 float* __restrict__ fineP) {
    const int c = blockIdx.x;
    const int t = threadIdx.x;
    const int d = t & 127;
    const int h = t >> 7;     // 0,1
    __shared__ float sums[2][128];
    __shared__ float scnt;
    if (t == 0) scnt = 0.f;
    __syncthreads();

    float s = 0.f;
    #pragma unroll 8
    for (int b = h; b < NBLK1; b += 2)
        s += part[(size_t)b * PART_STRIDE + c * D + d];
    sums[h][d] = s;

    // counts: thread t covers partials 2t, 2t+1
    float cl = part[(size_t)(2 * t) * PART_STRIDE + 12800 + c]
             + part[(size_t)(2 * t + 1) * PART_STRIDE + 12800 + c];
    for (int off = 32; off > 0; off >>= 1) cl += __shfl_down(cl, off);
    if ((t & 63) == 0) atomicAdd(&scnt, cl);
    __syncthreads();

    if (h == 0) fineP[c * D + d] = (sums[0][d] + sums[1][d]) / fmaxf(scnt, 1.0f);
}

// ---------------- K3: hierarchy + distance tables ----------------
__global__ __launch_bounds__(256) void k3_hier(const float* __restrict__ fineP,
                                               const int* __restrict__ f2m,
                                               const int* __restrict__ f2c,
                                               float* __restrict__ ws) {
    __shared__ float midP[C_MID * 129];
    __shared__ float coarP[C_COARSE * 129];
    __shared__ int   m2c[C_MID];
    const int t = threadIdx.x;

    for (int e = t; e < C_MID * D; e += 256) {
        int m = e >> 7, d = e & 127;
        float s = 0.f; int cnt = 0;
        for (int f = 0; f < C_FINE; ++f)
            if (f2m[f] == m) { s += fineP[f * D + d]; ++cnt; }
        midP[m * 129 + d] = s / (float)max(cnt, 1);
    }
    if (t < C_MID) {
        int mx = -2147483647;
        for (int f = 0; f < C_FINE; ++f)
            if (f2m[f] == t) mx = max(mx, f2c[f]);
        m2c[t] = mx;
    }
    __syncthreads();
    for (int e = t; e < C_COARSE * D; e += 256) {
        int cc = e >> 7, d = e & 127;
        float s = 0.f; int cnt = 0;
        for (int m = 0; m < C_MID; ++m)
            if (m2c[m] == cc) { s += midP[m * 129 + d]; ++cnt; }
        coarP[cc * 129 + d] = s / (float)max(cnt, 1);
    }
    __syncthreads();
    for (int e = t; e < C_MID * C_MID; e += 256) {
        int m1 = e / C_MID, m2 = e % C_MID;
        float ss = 0.f;
        for (int d = 0; d < D; ++d) {
            float df = midP[m1 * 129 + d] - midP[m2 * 129 + d];
            ss += df * df;
        }
        ws[DM_OFF + e] = sqrtf(ss + 1e-12f);
    }
    for (int e = t; e < C_COARSE * C_COARSE; e += 256) {
        int c1 = e / C_COARSE, c2 = e % C_COARSE;
        float ss = 0.f;
        for (int d = 0; d < D; ++d) {
            float df = coarP[c1 * 129 + d] - coarP[c2 * 129 + d];
            ss += df * df;
        }
        ws[DC_OFF + e] = sqrtf(ss + 1e-12f);
    }
    if (t < 6) ((double*)(ws + ACC_OFF))[t] = 0.0;   // zero accumulators
}

// ---------------- K4: all fine pairs -> 5 moments ----------------
__global__ __launch_bounds__(64) void k4_pairs(float* __restrict__ ws,
                                               const int* __restrict__ f2m,
                                               const int* __restrict__ f2c) {
    const int p = blockIdx.x * 64 + threadIdx.x;
    double st = 0, sp = 0, stp = 0, stt = 0, spp = 0;
    if (p < NPAIRS) {
        int i = 0, rem = p;
        while (rem >= C_FINE - 1 - i) { rem -= C_FINE - 1 - i; ++i; }
        int j = i + 1 + rem;

        const float4* Fi = (const float4*)(ws + FP_OFF + i * D);
        const float4* Fj = (const float4*)(ws + FP_OFF + j * D);
        float ss = 0.f;
        #pragma unroll
        for (int k = 0; k < D / 4; ++k) {
            float4 a = Fi[k], b = Fj[k];
            float dx = a.x - b.x, dy = a.y - b.y, dz = a.z - b.z, dw = a.w - b.w;
            ss += dx * dx + dy * dy + dz * dz + dw * dw;
        }
        float proto = sqrtf(ss + 1e-12f);
        float tree  = ws[DC_OFF + f2c[i] * C_COARSE + f2c[j]]
                    + ws[DM_OFF + f2m[i] * C_MID + f2m[j]];
        st = tree; sp = proto;
        stp = (double)tree * (double)proto;
        stt = (double)tree * (double)tree;
        spp = (double)proto * (double)proto;
    }
    for (int off = 32; off > 0; off >>= 1) {
        st  += __shfl_down(st, off);
        sp  += __shfl_down(sp, off);
        stp += __shfl_down(stp, off);
        stt += __shfl_down(stt, off);
        spp += __shfl_down(spp, off);
    }
    if (threadIdx.x == 0) {
        double* acc = (double*)(ws + ACC_OFF);
        atomicAdd(&acc[0], st);
        atomicAdd(&acc[1], sp);
        atomicAdd(&acc[2], stp);
        atomicAdd(&acc[3], stt);
        atomicAdd(&acc[4], spp);
    }
}

// ---------------- K5: finalize 1 - corr ----------------
__global__ void k5_final(const float* __restrict__ ws, float* __restrict__ out) {
    const double* acc = (const double*)(ws + ACC_OFF);
    double st = acc[0], sp = acc[1], stp = acc[2], stt = acc[3], spp = acc[4];
    const double n = (double)NPAIRS;
    double num = stp - st * sp / n;
    double dtt = stt - st * st / n;
    double dpp = spp - sp * sp / n;
    double corr = num / sqrt(dtt * dpp + 1e-12);
    out[0] = (float)(1.0 - corr);
}

extern "C" void kernel_launch(void* const* d_in, const int* in_sizes, int n_in,
                              void* d_out, int out_size, void* d_ws, size_t ws_size,
                              hipStream_t stream) {
    const float* rep = (const float*)d_in[0];
    const int*   tgt = (const int*)d_in[1];
    const int*   f2m = (const int*)d_in[2];
    const int*   f2c = (const int*)d_in[3];
    float* ws  = (float*)d_ws;
    float* out = (float*)d_out;

    hipLaunchKernelGGL(k1_partial, dim3(NBLK1), dim3(512), 0, stream, rep, tgt, ws);
    hipLaunchKernelGGL(k2_reduce, dim3(C_FINE), dim3(256), 0, stream,
                       ws + PART_OFF, ws + FP_OFF);
    hipLaunchKernelGGL(k3_hier, dim3(1), dim3(256), 0, stream,
                       ws + FP_OFF, f2m, f2c, ws);
    hipLaunchKernelGGL(k4_pairs, dim3((NPAIRS + 63) / 64), dim3(64), 0, stream,
                       ws, f2m, f2c);
    hipLaunchKernelGGL(k5_final, dim3(1), dim3(1), 0, stream, ws, out);
}

// Round 3
// 124.255 us; speedup vs baseline: 3.1729x; 2.3446x over previous
//
#include <hip/hip_runtime.h>
#include <math.h>

#define C_FINE   100
#define C_MID    20
#define C_COARSE 5
#define D        128
#define NROWS    262144
#define NPAIRS   4950   // 100*99/2

#define NBH      256            // histogram / scatter blocks
#define NBD      16             // gather blocks per class

// ws layout in floats
#define FP_OFF    0        // fine protos [100][128]
#define DM_OFF    12800    // mid dist table [20][20]
#define DC_OFF    13200    // coarse dist table [5][5]
#define ACC_OFF   13232    // 6 doubles (byte 52928, 8-aligned)
#define FSUM_OFF  13248    // fine sums [100][128]
#define HIST_OFF  26048    // int hist[256][100]
#define BOFF_OFF  51648    // int blockOff[256][100]
#define TOT_OFF   77248    // int total[100]
#define BASE_OFF  77348    // int base[100]
#define RIDX_OFF  77456    // int rowIdx[262144]

// ---------------- kA: per-block class histogram + zero fineSum ----------------
__global__ __launch_bounds__(256) void kA_hist(const int* __restrict__ tgt,
                                               float* __restrict__ ws) {
    __shared__ int hist[C_FINE];
    const int t = threadIdx.x, b = blockIdx.x;
    if (t < C_FINE) hist[t] = 0;
    __syncthreads();
    const int4 cs = ((const int4*)tgt)[b * 256 + t];
    atomicAdd(&hist[cs.x], 1); atomicAdd(&hist[cs.y], 1);
    atomicAdd(&hist[cs.z], 1); atomicAdd(&hist[cs.w], 1);
    __syncthreads();
    int* histg = (int*)ws + HIST_OFF;
    if (t < C_FINE) histg[b * C_FINE + t] = hist[t];
    if (t < 50) ws[FSUM_OFF + b * 50 + t] = 0.f;   // 256*50 = 12800
}

// ---------------- kB: per-class exclusive scan over 256 block-hists ----------------
__global__ __launch_bounds__(256) void kB_scan(float* __restrict__ ws) {
    __shared__ int sc[NBH];
    const int c = blockIdx.x, t = threadIdx.x;
    const int* histg = (const int*)ws + HIST_OFF;
    int x = histg[t * C_FINE + c];
    sc[t] = x;
    __syncthreads();
    for (int off = 1; off < NBH; off <<= 1) {
        int v = (t >= off) ? sc[t - off] : 0;
        __syncthreads();
        sc[t] += v;
        __syncthreads();
    }
    ((int*)ws + BOFF_OFF)[t * C_FINE + c] = sc[t] - x;
    if (t == NBH - 1) ((int*)ws + TOT_OFF)[c] = sc[t];
}

// ---------------- kB2: exclusive scan over class totals -> base ----------------
__global__ __launch_bounds__(128) void kB2_base(float* __restrict__ ws) {
    __shared__ int sc[128];
    const int t = threadIdx.x;
    const int* tot = (const int*)ws + TOT_OFF;
    int x = (t < C_FINE) ? tot[t] : 0;
    sc[t] = x;
    __syncthreads();
    for (int off = 1; off < 128; off <<= 1) {
        int v = (t >= off) ? sc[t - off] : 0;
        __syncthreads();
        sc[t] += v;
        __syncthreads();
    }
    if (t < C_FINE) ((int*)ws + BASE_OFF)[t] = sc[t] - x;
}

// ---------------- kC: scatter row indices into class buckets ----------------
__global__ __launch_bounds__(256) void kC_scatter(const int* __restrict__ tgt,
                                                  float* __restrict__ ws) {
    __shared__ int cnt[C_FINE];
    const int t = threadIdx.x, b = blockIdx.x;
    if (t < C_FINE) cnt[t] = 0;
    __syncthreads();
    const int4 cs = ((const int4*)tgt)[b * 256 + t];
    const int* base = (const int*)ws + BASE_OFF;
    const int* boff = (const int*)ws + BOFF_OFF;
    int* ridx = (int*)ws + RIDX_OFF;
    const int r0 = b * 1024 + t * 4;
    int c, rk;
    c = cs.x; rk = atomicAdd(&cnt[c], 1); ridx[base[c] + boff[b * C_FINE + c] + rk] = r0;
    c = cs.y; rk = atomicAdd(&cnt[c], 1); ridx[base[c] + boff[b * C_FINE + c] + rk] = r0 + 1;
    c = cs.z; rk = atomicAdd(&cnt[c], 1); ridx[base[c] + boff[b * C_FINE + c] + rk] = r0 + 2;
    c = cs.w; rk = atomicAdd(&cnt[c], 1); ridx[base[c] + boff[b * C_FINE + c] + rk] = r0 + 3;
}

// ---------------- kD: gather rows of one class, sum (no scatter atomics) ----------------
__global__ __launch_bounds__(256) void kD_gather(const float* __restrict__ rep,
                                                 float* __restrict__ ws) {
    const int c = blockIdx.x / NBD, j = blockIdx.x % NBD;
    const int t = threadIdx.x, s = t >> 5, lane = t & 31;
    const int nt = ((const int*)ws + TOT_OFF)[c];
    const int b0 = ((const int*)ws + BASE_OFF)[c];
    const int* ridx = (const int*)ws + RIDX_OFF;
    const float4* rep4 = (const float4*)rep;

    float4 acc = make_float4(0.f, 0.f, 0.f, 0.f);
    int k = j * 8 + s;
    int r = (k < nt) ? ridx[b0 + k] : 0;
    while (k < nt) {
        int k2 = k + NBD * 8;
        int r2 = (k2 < nt) ? ridx[b0 + k2] : 0;   // prefetch next index
        float4 v = rep4[(size_t)r * 32 + lane];
        acc.x += v.x; acc.y += v.y; acc.z += v.z; acc.w += v.w;
        k = k2; r = r2;
    }
    __shared__ float red[8][128];
    *(float4*)&red[s][lane * 4] = acc;
    __syncthreads();
    if (t < D) {
        float sum = 0.f;
        #pragma unroll
        for (int q = 0; q < 8; ++q) sum += red[q][t];
        atomicAdd(ws + FSUM_OFF + c * D + t, sum);
    }
}

// ---------------- kE: normalize -> fine prototypes ----------------
__global__ __launch_bounds__(128) void kE_norm(float* __restrict__ ws) {
    const int c = blockIdx.x, t = threadIdx.x;
    const int nt = ((const int*)ws + TOT_OFF)[c];
    ws[FP_OFF + c * D + t] = ws[FSUM_OFF + c * D + t] / fmaxf((float)nt, 1.f);
}

// ---------------- K3: hierarchy + distance tables ----------------
__global__ __launch_bounds__(256) void k3_hier(const float* __restrict__ fineP,
                                               const int* __restrict__ f2m,
                                               const int* __restrict__ f2c,
                                               float* __restrict__ ws) {
    __shared__ float midP[C_MID * 129];
    __shared__ float coarP[C_COARSE * 129];
    __shared__ int   m2c[C_MID];
    __shared__ int   sf2m[C_FINE], sf2c[C_FINE];
    const int t = threadIdx.x;
    if (t < C_FINE) { sf2m[t] = f2m[t]; sf2c[t] = f2c[t]; }
    __syncthreads();

    for (int e = t; e < C_MID * D; e += 256) {
        int m = e >> 7, d = e & 127;
        float s = 0.f; int cnt = 0;
        for (int f = 0; f < C_FINE; ++f)
            if (sf2m[f] == m) { s += fineP[f * D + d]; ++cnt; }
        midP[m * 129 + d] = s / (float)max(cnt, 1);
    }
    if (t < C_MID) {
        int mx = -2147483647;
        for (int f = 0; f < C_FINE; ++f)
            if (sf2m[f] == t) mx = max(mx, sf2c[f]);
        m2c[t] = mx;
    }
    __syncthreads();
    for (int e = t; e < C_COARSE * D; e += 256) {
        int cc = e >> 7, d = e & 127;
        float s = 0.f; int cnt = 0;
        for (int m = 0; m < C_MID; ++m)
            if (m2c[m] == cc) { s += midP[m * 129 + d]; ++cnt; }
        coarP[cc * 129 + d] = s / (float)max(cnt, 1);
    }
    __syncthreads();
    for (int e = t; e < C_MID * C_MID; e += 256) {
        int m1 = e / C_MID, m2 = e % C_MID;
        float ss = 0.f;
        for (int d = 0; d < D; ++d) {
            float df = midP[m1 * 129 + d] - midP[m2 * 129 + d];
            ss += df * df;
        }
        ws[DM_OFF + e] = sqrtf(ss + 1e-12f);
    }
    for (int e = t; e < C_COARSE * C_COARSE; e += 256) {
        int c1 = e / C_COARSE, c2 = e % C_COARSE;
        float ss = 0.f;
        for (int d = 0; d < D; ++d) {
            float df = coarP[c1 * 129 + d] - coarP[c2 * 129 + d];
            ss += df * df;
        }
        ws[DC_OFF + e] = sqrtf(ss + 1e-12f);
    }
    if (t < 6) ((double*)(ws + ACC_OFF))[t] = 0.0;   // zero accumulators
}

// ---------------- K4: all fine pairs -> 5 moments ----------------
__global__ __launch_bounds__(64) void k4_pairs(float* __restrict__ ws,
                                               const int* __restrict__ f2m,
                                               const int* __restrict__ f2c) {
    const int p = blockIdx.x * 64 + threadIdx.x;
    double st = 0, sp = 0, stp = 0, stt = 0, spp = 0;
    if (p < NPAIRS) {
        int i = 0, rem = p;
        while (rem >= C_FINE - 1 - i) { rem -= C_FINE - 1 - i; ++i; }
        int j = i + 1 + rem;

        const float4* Fi = (const float4*)(ws + FP_OFF + i * D);
        const float4* Fj = (const float4*)(ws + FP_OFF + j * D);
        float ss = 0.f;
        #pragma unroll
        for (int k = 0; k < D / 4; ++k) {
            float4 a = Fi[k], b = Fj[k];
            float dx = a.x - b.x, dy = a.y - b.y, dz = a.z - b.z, dw = a.w - b.w;
            ss += dx * dx + dy * dy + dz * dz + dw * dw;
        }
        float proto = sqrtf(ss + 1e-12f);
        float tree  = ws[DC_OFF + f2c[i] * C_COARSE + f2c[j]]
                    + ws[DM_OFF + f2m[i] * C_MID + f2m[j]];
        st = tree; sp = proto;
        stp = (double)tree * (double)proto;
        stt = (double)tree * (double)tree;
        spp = (double)proto * (double)proto;
    }
    for (int off = 32; off > 0; off >>= 1) {
        st  += __shfl_down(st, off);
        sp  += __shfl_down(sp, off);
        stp += __shfl_down(stp, off);
        stt += __shfl_down(stt, off);
        spp += __shfl_down(spp, off);
    }
    if (threadIdx.x == 0) {
        double* acc = (double*)(ws + ACC_OFF);
        atomicAdd(&acc[0], st);
        atomicAdd(&acc[1], sp);
        atomicAdd(&acc[2], stp);
        atomicAdd(&acc[3], stt);
        atomicAdd(&acc[4], spp);
    }
}

// ---------------- K5: finalize 1 - corr ----------------
__global__ void k5_final(const float* __restrict__ ws, float* __restrict__ out) {
    const double* acc = (const double*)(ws + ACC_OFF);
    double st = acc[0], sp = acc[1], stp = acc[2], stt = acc[3], spp = acc[4];
    const double n = (double)NPAIRS;
    double num = stp - st * sp / n;
    double dtt = stt - st * st / n;
    double dpp = spp - sp * sp / n;
    double corr = num / sqrt(dtt * dpp + 1e-12);
    out[0] = (float)(1.0 - corr);
}

extern "C" void kernel_launch(void* const* d_in, const int* in_sizes, int n_in,
                              void* d_out, int out_size, void* d_ws, size_t ws_size,
                              hipStream_t stream) {
    const float* rep = (const float*)d_in[0];
    const int*   tgt = (const int*)d_in[1];
    const int*   f2m = (const int*)d_in[2];
    const int*   f2c = (const int*)d_in[3];
    float* ws  = (float*)d_ws;
    float* out = (float*)d_out;

    hipLaunchKernelGGL(kA_hist,    dim3(NBH),           dim3(256), 0, stream, tgt, ws);
    hipLaunchKernelGGL(kB_scan,    dim3(C_FINE),        dim3(NBH), 0, stream, ws);
    hipLaunchKernelGGL(kB2_base,   dim3(1),             dim3(128), 0, stream, ws);
    hipLaunchKernelGGL(kC_scatter, dim3(NBH),           dim3(256), 0, stream, tgt, ws);
    hipLaunchKernelGGL(kD_gather,  dim3(C_FINE * NBD),  dim3(256), 0, stream, rep, ws);
    hipLaunchKernelGGL(kE_norm,    dim3(C_FINE),        dim3(128), 0, stream, ws);
    hipLaunchKernelGGL(k3_hier,    dim3(1),             dim3(256), 0, stream,
                       ws + FP_OFF, f2m, f2c, ws);
    hipLaunchKernelGGL(k4_pairs,   dim3((NPAIRS + 63) / 64), dim3(64), 0, stream,
                       ws, f2m, f2c);
    hipLaunchKernelGGL(k5_final,   dim3(1),             dim3(1),   0, stream, ws, out);
}

// Round 4
// 73.637 us; speedup vs baseline: 5.3539x; 1.6874x over previous
//
#include <hip/hip_runtime.h>
#include <math.h>

#define C_FINE   100
#define C_MID    20
#define C_COARSE 5
#define D        128
#define NROWS    262144
#define NPAIRS   4950   // 100*99/2

#define NBH      256            // histogram / scatter blocks
#define NBD      16             // gather blocks per class

// ws layout in floats
#define FP_OFF    0        // fine protos [100][128]
#define DM_OFF    12800    // mid dist table [20][20]
#define DC_OFF    13200    // coarse dist table [5][5]
#define ACC_OFF   13232    // 6 doubles (byte 52928, 8-aligned)
#define FSUM_OFF  13248    // fine sums [100][128]
#define HIST_OFF  26048    // int hist[256][100]
#define BOFF_OFF  51648    // int blockOff[256][100]
#define TOT_OFF   77248    // int total[100]
#define BASE_OFF  77348    // int base[100]
#define RIDX_OFF  77456    // int rowIdx[262144]

// ---------------- kA: per-block class histogram + zero fineSum ----------------
__global__ __launch_bounds__(256) void kA_hist(const int* __restrict__ tgt,
                                               float* __restrict__ ws) {
    __shared__ int hist[C_FINE];
    const int t = threadIdx.x, b = blockIdx.x;
    if (t < C_FINE) hist[t] = 0;
    __syncthreads();
    const int4 cs = ((const int4*)tgt)[b * 256 + t];
    atomicAdd(&hist[cs.x], 1); atomicAdd(&hist[cs.y], 1);
    atomicAdd(&hist[cs.z], 1); atomicAdd(&hist[cs.w], 1);
    __syncthreads();
    int* histg = (int*)ws + HIST_OFF;
    if (t < C_FINE) histg[b * C_FINE + t] = hist[t];
    if (t < 50) ws[FSUM_OFF + b * 50 + t] = 0.f;   // 256*50 = 12800
}

// ---------------- kB: per-class exclusive scan over 256 block-hists ----------------
__global__ __launch_bounds__(256) void kB_scan(float* __restrict__ ws) {
    __shared__ int sc[NBH];
    const int c = blockIdx.x, t = threadIdx.x;
    const int* histg = (const int*)ws + HIST_OFF;
    int x = histg[t * C_FINE + c];
    sc[t] = x;
    __syncthreads();
    for (int off = 1; off < NBH; off <<= 1) {
        int v = (t >= off) ? sc[t - off] : 0;
        __syncthreads();
        sc[t] += v;
        __syncthreads();
    }
    ((int*)ws + BOFF_OFF)[t * C_FINE + c] = sc[t] - x;
    if (t == NBH - 1) ((int*)ws + TOT_OFF)[c] = sc[t];
}

// ---------------- kB2: exclusive scan over class totals -> base ----------------
__global__ __launch_bounds__(128) void kB2_base(float* __restrict__ ws) {
    __shared__ int sc[128];
    const int t = threadIdx.x;
    const int* tot = (const int*)ws + TOT_OFF;
    int x = (t < C_FINE) ? tot[t] : 0;
    sc[t] = x;
    __syncthreads();
    for (int off = 1; off < 128; off <<= 1) {
        int v = (t >= off) ? sc[t - off] : 0;
        __syncthreads();
        sc[t] += v;
        __syncthreads();
    }
    if (t < C_FINE) ((int*)ws + BASE_OFF)[t] = sc[t] - x;
}

// ---------------- kC: scatter row indices into class buckets ----------------
__global__ __launch_bounds__(256) void kC_scatter(const int* __restrict__ tgt,
                                                  float* __restrict__ ws) {
    __shared__ int cnt[C_FINE];
    const int t = threadIdx.x, b = blockIdx.x;
    if (t < C_FINE) cnt[t] = 0;
    __syncthreads();
    const int4 cs = ((const int4*)tgt)[b * 256 + t];
    const int* base = (const int*)ws + BASE_OFF;
    const int* boff = (const int*)ws + BOFF_OFF;
    int* ridx = (int*)ws + RIDX_OFF;
    const int r0 = b * 1024 + t * 4;
    int c, rk;
    c = cs.x; rk = atomicAdd(&cnt[c], 1); ridx[base[c] + boff[b * C_FINE + c] + rk] = r0;
    c = cs.y; rk = atomicAdd(&cnt[c], 1); ridx[base[c] + boff[b * C_FINE + c] + rk] = r0 + 1;
    c = cs.z; rk = atomicAdd(&cnt[c], 1); ridx[base[c] + boff[b * C_FINE + c] + rk] = r0 + 2;
    c = cs.w; rk = atomicAdd(&cnt[c], 1); ridx[base[c] + boff[b * C_FINE + c] + rk] = r0 + 3;
}

// ---------------- kD: gather rows of one class, sum (no scatter atomics) ----------------
__global__ __launch_bounds__(256) void kD_gather(const float* __restrict__ rep,
                                                 float* __restrict__ ws) {
    const int c = blockIdx.x / NBD, j = blockIdx.x % NBD;
    const int t = threadIdx.x, s = t >> 5, lane = t & 31;
    const int nt = ((const int*)ws + TOT_OFF)[c];
    const int b0 = ((const int*)ws + BASE_OFF)[c];
    const int* ridx = (const int*)ws + RIDX_OFF;
    const float4* rep4 = (const float4*)rep;

    float4 acc = make_float4(0.f, 0.f, 0.f, 0.f);
    int k = j * 8 + s;
    int r = (k < nt) ? ridx[b0 + k] : 0;
    while (k < nt) {
        int k2 = k + NBD * 8;
        int r2 = (k2 < nt) ? ridx[b0 + k2] : 0;   // prefetch next index
        float4 v = rep4[(size_t)r * 32 + lane];
        acc.x += v.x; acc.y += v.y; acc.z += v.z; acc.w += v.w;
        k = k2; r = r2;
    }
    __shared__ float red[8][128];
    *(float4*)&red[s][lane * 4] = acc;
    __syncthreads();
    if (t < D) {
        float sum = 0.f;
        #pragma unroll
        for (int q = 0; q < 8; ++q) sum += red[q][t];
        atomicAdd(ws + FSUM_OFF + c * D + t, sum);
    }
}

// ---------------- k3: normalize + hierarchy + distance tables (all in LDS) ----------------
__global__ __launch_bounds__(256) void k3_hier(const int* __restrict__ f2m,
                                               const int* __restrict__ f2c,
                                               float* __restrict__ ws) {
    __shared__ float fineP[C_FINE][D];        // 51.2 KB
    __shared__ float midP[C_MID][D + 1];      // 10.3 KB
    __shared__ float coarP[C_COARSE][D + 1];  // 2.6 KB
    __shared__ int   sf2m[C_FINE], sf2c[C_FINE], m2c[C_MID];
    __shared__ float midCnt[C_MID], coarCnt[C_COARSE];
    const int t = threadIdx.x;

    if (t < C_FINE) { sf2m[t] = f2m[t]; sf2c[t] = f2c[t]; }
    // stage counts
    __shared__ float sTot[C_FINE];
    if (t < C_FINE) sTot[t] = (float)((const int*)ws + TOT_OFF)[t];
    for (int e = t; e < C_MID * (D + 1); e += 256) ((float*)midP)[e] = 0.f;
    for (int e = t; e < C_COARSE * (D + 1); e += 256) ((float*)coarP)[e] = 0.f;
    __syncthreads();

    // normalize fine sums -> fineP (LDS + global for k4)
    for (int e = t; e < C_FINE * D; e += 256) {
        int c = e >> 7, d = e & 127;
        float v = ws[FSUM_OFF + e] / fmaxf(sTot[c], 1.f);
        fineP[c][d] = v;
        ws[FP_OFF + e] = v;
    }
    if (t < C_MID) {
        int cnt = 0, mx = -2147483647;
        for (int f = 0; f < C_FINE; ++f)
            if (sf2m[f] == t) { ++cnt; mx = max(mx, sf2c[f]); }
        midCnt[t] = (float)max(cnt, 1);
        m2c[t] = mx;
    }
    __syncthreads();

    // mid sums: one pass over fines, dim-thread owns column d
    if (t < D) {
        const int d = t;
        for (int f = 0; f < C_FINE; ++f)
            midP[sf2m[f]][d] += fineP[f][d];
        for (int m = 0; m < C_MID; ++m)
            midP[m][d] /= midCnt[m];
    }
    if (t >= 128 && t < 128 + C_COARSE) {
        int cc = t - 128, cnt = 0;
        for (int m = 0; m < C_MID; ++m) if (m2c[m] == cc) ++cnt;
        coarCnt[cc] = (float)max(cnt, 1);
    }
    __syncthreads();

    // coarse sums
    if (t < D) {
        const int d = t;
        for (int m = 0; m < C_MID; ++m)
            coarP[m2c[m]][d] += midP[m][d];
        for (int cc = 0; cc < C_COARSE; ++cc)
            coarP[cc][d] /= coarCnt[cc];
    }
    __syncthreads();

    // mid distance table [20][20]
    for (int e = t; e < C_MID * C_MID; e += 256) {
        int m1 = e / C_MID, m2 = e % C_MID;
        float ss = 0.f;
        #pragma unroll 8
        for (int d = 0; d < D; ++d) {
            float df = midP[m1][d] - midP[m2][d];
            ss += df * df;
        }
        ws[DM_OFF + e] = sqrtf(ss + 1e-12f);
    }
    // coarse distance table [5][5]
    for (int e = t; e < C_COARSE * C_COARSE; e += 256) {
        int c1 = e / C_COARSE, c2 = e % C_COARSE;
        float ss = 0.f;
        #pragma unroll 8
        for (int d = 0; d < D; ++d) {
            float df = coarP[c1][d] - coarP[c2][d];
            ss += df * df;
        }
        ws[DC_OFF + e] = sqrtf(ss + 1e-12f);
    }
    if (t < 6) ((double*)(ws + ACC_OFF))[t] = 0.0;   // zero accumulators
}

// ---------------- K4: all fine pairs -> 5 moments ----------------
__global__ __launch_bounds__(64) void k4_pairs(float* __restrict__ ws,
                                               const int* __restrict__ f2m,
                                               const int* __restrict__ f2c) {
    const int p = blockIdx.x * 64 + threadIdx.x;
    double st = 0, sp = 0, stp = 0, stt = 0, spp = 0;
    if (p < NPAIRS) {
        int i = 0, rem = p;
        while (rem >= C_FINE - 1 - i) { rem -= C_FINE - 1 - i; ++i; }
        int j = i + 1 + rem;

        const float4* Fi = (const float4*)(ws + FP_OFF + i * D);
        const float4* Fj = (const float4*)(ws + FP_OFF + j * D);
        float ss = 0.f;
        #pragma unroll
        for (int k = 0; k < D / 4; ++k) {
            float4 a = Fi[k], b = Fj[k];
            float dx = a.x - b.x, dy = a.y - b.y, dz = a.z - b.z, dw = a.w - b.w;
            ss += dx * dx + dy * dy + dz * dz + dw * dw;
        }
        float proto = sqrtf(ss + 1e-12f);
        float tree  = ws[DC_OFF + f2c[i] * C_COARSE + f2c[j]]
                    + ws[DM_OFF + f2m[i] * C_MID + f2m[j]];
        st = tree; sp = proto;
        stp = (double)tree * (double)proto;
        stt = (double)tree * (double)tree;
        spp = (double)proto * (double)proto;
    }
    for (int off = 32; off > 0; off >>= 1) {
        st  += __shfl_down(st, off);
        sp  += __shfl_down(sp, off);
        stp += __shfl_down(stp, off);
        stt += __shfl_down(stt, off);
        spp += __shfl_down(spp, off);
    }
    if (threadIdx.x == 0) {
        double* acc = (double*)(ws + ACC_OFF);
        atomicAdd(&acc[0], st);
        atomicAdd(&acc[1], sp);
        atomicAdd(&acc[2], stp);
        atomicAdd(&acc[3], stt);
        atomicAdd(&acc[4], spp);
    }
}

// ---------------- K5: finalize 1 - corr ----------------
__global__ void k5_final(const float* __restrict__ ws, float* __restrict__ out) {
    const double* acc = (const double*)(ws + ACC_OFF);
    double st = acc[0], sp = acc[1], stp = acc[2], stt = acc[3], spp = acc[4];
    const double n = (double)NPAIRS;
    double num = stp - st * sp / n;
    double dtt = stt - st * st / n;
    double dpp = spp - sp * sp / n;
    double corr = num / sqrt(dtt * dpp + 1e-12);
    out[0] = (float)(1.0 - corr);
}

extern "C" void kernel_launch(void* const* d_in, const int* in_sizes, int n_in,
                              void* d_out, int out_size, void* d_ws, size_t ws_size,
                              hipStream_t stream) {
    const float* rep = (const float*)d_in[0];
    const int*   tgt = (const int*)d_in[1];
    const int*   f2m = (const int*)d_in[2];
    const int*   f2c = (const int*)d_in[3];
    float* ws  = (float*)d_ws;
    float* out = (float*)d_out;

    hipLaunchKernelGGL(kA_hist,    dim3(NBH),           dim3(256), 0, stream, tgt, ws);
    hipLaunchKernelGGL(kB_scan,    dim3(C_FINE),        dim3(NBH), 0, stream, ws);
    hipLaunchKernelGGL(kB2_base,   dim3(1),             dim3(128), 0, stream, ws);
    hipLaunchKernelGGL(kC_scatter, dim3(NBH),           dim3(256), 0, stream, tgt, ws);
    hipLaunchKernelGGL(kD_gather,  dim3(C_FINE * NBD),  dim3(256), 0, stream, rep, ws);
    hipLaunchKernelGGL(k3_hier,    dim3(1),             dim3(256), 0, stream, f2m, f2c, ws);
    hipLaunchKernelGGL(k4_pairs,   dim3((NPAIRS + 63) / 64), dim3(64), 0, stream,
                       ws, f2m, f2c);
    hipLaunchKernelGGL(k5_final,   dim3(1),             dim3(1),   0, stream, ws, out);
}